// Round 7
// baseline (71.683 us; speedup 1.0000x reference)
//
#include <hip/hip_runtime.h>

// Problem constants (from reference): N_IN=16, T_IN=64, V=4, DEG=4 -> C=5, K=9
#define NINP 16
#define TIN 64
#define NV 4
#define NC 5
#define NK 9
#define T_ROWS 1025                 // 16*64 + 1 (const row)
#define NPAIR (1025 * 1025)         // 1,050,625
#define UNDER_SZ (T_ROWS * NV * NC) // 20500  (output 0)
#define OQ_OFF UNDER_SZ
#define OQ_SQ_SZ (NPAIR * NV * NK)          // 37,822,500
#define TAIL_ELEMS ((T_ROWS + 1) * NV * NK) // 36,936 (lin rows + const row)
#define DEG_OFF (OQ_OFF + OQ_SQ_SZ + TAIL_ELEMS) // 37,879,936
// ws layout: floats [0, 20500) = over polys PREMULTIPLIED by C(4,i);
//            long-long partials at ll index 10252
#define WS_POVER 0
#define L_PART_LL 10252           // byte offset 82016, 8B aligned, past over polys
#define FIXED_SCALE 16777216.0f   // 2^24

#define PREP_ELEM_BLOCKS 161      // 161*256 = 41216 >= 2*20500
#define PREP_L_BLOCKS 4           // 4*256 = 1024 threads, rows 0..1023 (+row 1024 extra)
#define PAIR_BLOCKS 4105          // ceil(1050625/256)
#define TAIL_BLOCKS 145           // ceil(36936/256)

__device__ __forceinline__ int count_nz16(const float* __restrict__ w) {
    int c = 0;
#pragma unroll
    for (int n = 0; n < NINP; n++) c += (w[n] != 0.0f) ? 1 : 0;
    return c;
}

__device__ __forceinline__ int kth_nz16(const float* __restrict__ w, int k) {
    int c = 0, r = 0;
#pragma unroll
    for (int n = 0; n < NINP; n++) {
        bool nz = (w[n] != 0.0f);
        if (nz && c == k) r = n;
        c += nz ? 1 : 0;
    }
    return r;
}

// value of the `under` polynomial array at (row r, var v, coeff c)
__device__ __forceinline__ float under_val(const float* __restrict__ ui,
                                           const float* __restrict__ oi,
                                           const float* __restrict__ posw,
                                           const float* __restrict__ negw,
                                           float bias, int r, int v, int c) {
    if (r < 1024) {
        int g = r >> 6, tt = r & 63;
        int nNeg = count_nz16(negw);
        if (g < nNeg) {
            int n = kth_nz16(negw, g);
            return oi[((n * TIN + tt) * NV + v) * NC + c] * ((v == 0) ? negw[n] : 1.0f);
        }
        int n = kth_nz16(posw, g - nNeg);
        return ui[((n * TIN + tt) * NV + v) * NC + c] * ((v == 0) ? posw[n] : 1.0f);
    }
    return (v == 0) ? bias : 1.0f;
}

// Kernel 1: blocks [0,161): build `under` (-> d_out) and C4-premultiplied `over`
//           (-> ws) + deg outputs.
//           blocks [161,165): interval lower bound per under-row, deterministic
//           fixed-point int64 block reduction -> 4 partials in ws.
__global__ __launch_bounds__(256) void prep_kernel(
    const float* __restrict__ ui, const float* __restrict__ oi,
    const float* __restrict__ posw, const float* __restrict__ negw,
    const float* __restrict__ bias,
    const int* __restrict__ udeg, const int* __restrict__ odeg,
    float* __restrict__ out, float* __restrict__ ws) {
    const int bid = blockIdx.x;
    const int t = threadIdx.x;

    if (bid < PREP_ELEM_BLOCKS) {
        int gid = bid * 256 + t;
        if (gid < NV) {
            int m = 0;
            for (int n = 0; n < NINP; n++) {
                int a = udeg[n * NV + gid];
                int b = odeg[n * NV + gid];
                m = max(m, max(a, b));
            }
            out[DEG_OFF + gid] = (float)m;
            out[DEG_OFF + NV + gid] = 2.0f * (float)m;
        }
        if (gid < UNDER_SZ) {
            int r = gid / 20, rem = gid - r * 20, v = rem / 5, c = rem - v * 5;
            out[gid] = under_val(ui, oi, posw, negw, bias[0], r, v, c);
        } else if (gid < 2 * UNDER_SZ) {
            // over element: rows = [over_in[pos]*pos_w ; under_in[neg]*neg_w ; const]
            int e = gid - UNDER_SZ;
            int r = e / 20, rem = e - r * 20, v = rem / 5, c = rem - v * 5;
            float val;
            if (r < 1024) {
                int g = r >> 6, tt = r & 63;
                int nPos = count_nz16(posw);
                if (g < nPos) {
                    int n = kth_nz16(posw, g);
                    val = oi[((n * TIN + tt) * NV + v) * NC + c] * ((v == 0) ? posw[n] : 1.0f);
                } else {
                    int n = kth_nz16(negw, g - nPos);
                    val = ui[((n * TIN + tt) * NV + v) * NC + c] * ((v == 0) ? negw[n] : 1.0f);
                }
            } else {
                val = (v == 0) ? bias[0] : 1.0f;
            }
            // premultiply by C(4,c): consumed as conv operand by main & tail
            const float c4 = (c == 0 || c == 4) ? 1.f : ((c == 2) ? 6.f : 4.f);
            ws[WS_POVER + e] = val * c4;
        }
    } else {
        // l partial: rows (bid-161)*256 + t
        __shared__ long long s[256];
        const float b0 = bias[0];
        int r = (bid - PREP_ELEM_BLOCKS) * 256 + t;
        float tlo = 0.f, thi = 0.f;
#pragma unroll
        for (int v = 0; v < NV; v++) {
            float lo = under_val(ui, oi, posw, negw, b0, r, v, 0), hi = lo;
#pragma unroll
            for (int c = 1; c < NC; c++) {
                float x = under_val(ui, oi, posw, negw, b0, r, v, c);
                lo = fminf(lo, x);
                hi = fmaxf(hi, x);
            }
            if (v == 0) { tlo = lo; thi = hi; }
            else {
                float p0 = tlo * lo, p1 = tlo * hi, p2 = thi * lo, p3 = thi * hi;
                tlo = fminf(fminf(p0, p1), fminf(p2, p3));
                thi = fmaxf(fmaxf(p0, p1), fmaxf(p2, p3));
            }
        }
        long long acc = __float2ll_rn(tlo * FIXED_SCALE);
        if (bid == PREP_ELEM_BLOCKS && t == 0) {
            // const row 1024: interval product = bias (all other vars are exactly 1)
            acc += __float2ll_rn(b0 * FIXED_SCALE);
        }
        s[t] = acc;
        __syncthreads();
        for (int off = 128; off > 0; off >>= 1) {
            if (t < off) s[t] += s[t + off];
            __syncthreads();
        }
        if (t == 0) ((long long*)ws)[L_PART_LL + (bid - PREP_ELEM_BLOCKS)] = s[0];
    }
}

__device__ __forceinline__ float c4_of(int j) {
    if (j == 0 || j == 4) return 1.f;
    if (j == 1 || j == 3) return 4.f;
    if (j == 2) return 6.f;
    return 0.f;
}

// Kernel 2: blocks [0,4105): pair-product rows. 1 thread = 1 (a,b) pair = 36 floats
//   computed in registers and stored DIRECTLY as 9 dwordx4 (no LDS, no barrier).
//   Rows arrive C4-premultiplied from prep; ascale folded into the 5 v0 coeffs of A.
// Blocks [4105,4250): lin+const tail.
__global__ __launch_bounds__(256) void main_kernel(const float* __restrict__ P,
                                                   const long long* __restrict__ lpart,
                                                   float* __restrict__ out) {
    const int bid = blockIdx.x;
    const int t = threadIdx.x;
    const long long llv = lpart[0] + lpart[1] + lpart[2] + lpart[3];
    const float l = (float)llv * (1.0f / FIXED_SCALE);

    if (bid < PAIR_BLOCKS) {
        const int p = bid * 256 + t;
        if (p >= NPAIR) return;
        const float ascale = -0.25f / l; // a = 1/(-4l)
        const int ai = p / 1025;
        const int bi = p - ai * 1025;
        float pa[20], pb[20];
        const float4* A4 = reinterpret_cast<const float4*>(P + ai * 20);
        const float4* B4 = reinterpret_cast<const float4*>(P + bi * 20);
#pragma unroll
        for (int q = 0; q < 5; q++) {
            float4 x = A4[q];
            pa[4 * q] = x.x; pa[4 * q + 1] = x.y; pa[4 * q + 2] = x.z; pa[4 * q + 3] = x.w;
            float4 y = B4[q];
            pb[4 * q] = y.x; pb[4 * q + 1] = y.y; pb[4 * q + 2] = y.z; pb[4 * q + 3] = y.w;
        }
        // fold ascale into A's v0 slice (5 mults replace 9 per-k scales)
#pragma unroll
        for (int i = 0; i < 5; i++) pa[i] *= ascale;

        const float invC8[9] = {1.f, 0.125f, 1.f / 28.f, 1.f / 56.f, 1.f / 70.f,
                                1.f / 56.f, 1.f / 28.f, 0.125f, 1.f};
        float o[36];
#pragma unroll
        for (int v = 0; v < NV; v++) {
            float cc[9];
#pragma unroll
            for (int k = 0; k < 9; k++) cc[k] = 0.f;
#pragma unroll
            for (int i = 0; i < 5; i++)
#pragma unroll
                for (int j = 0; j < 5; j++) cc[i + j] += pa[v * 5 + i] * pb[v * 5 + j];
#pragma unroll
            for (int k = 0; k < 9; k++) o[v * 9 + k] = cc[k] * invC8[k];
        }
        // 9 direct dwordx4 stores; base 16B-aligned (20500 + 36p ≡ 0 mod 4)
        float4* out4 = reinterpret_cast<float4*>(out) + (5125 + p * 9);
#pragma unroll
        for (int q = 0; q < 9; q++)
            out4[q] = make_float4(o[4 * q], o[4 * q + 1], o[4 * q + 2], o[4 * q + 3]);
    } else {
        // tail: 1025 elevated-linear rows (b=0.5 on v0) + 1 const row (c=-l/4, 1,1,1)
        // P rows are C4-premultiplied, so E[i,k] contribution drops its C4[i] factor.
        int idx = (bid - PAIR_BLOCKS) * 256 + t;
        if (idx >= TAIL_ELEMS) return;
        int rl = idx / 36, rem = idx - rl * 36, v = rem / 9, k = rem - v * 9;
        const float invC8[9] = {1.f, 0.125f, 1.f / 28.f, 1.f / 56.f, 1.f / 70.f,
                                1.f / 56.f, 1.f / 28.f, 0.125f, 1.f};
        float val;
        if (rl < T_ROWS) {
            float acc = 0.f;
#pragma unroll
            for (int i = 0; i < 5; i++) {
                acc += P[rl * 20 + v * 5 + i] * c4_of(k - i);
            }
            val = acc * invC8[k] * ((v == 0) ? 0.5f : 1.0f);
        } else {
            val = (v == 0) ? (-0.25f * l) : 1.0f;
        }
        out[OQ_OFF + (long)NPAIR * 36 + idx] = val;
    }
}

extern "C" void kernel_launch(void* const* d_in, const int* in_sizes, int n_in,
                              void* d_out, int out_size, void* d_ws, size_t ws_size,
                              hipStream_t stream) {
    const float* ui   = (const float*)d_in[0];
    const float* oi   = (const float*)d_in[1];
    const float* posw = (const float*)d_in[2];
    const float* negw = (const float*)d_in[3];
    const float* bias = (const float*)d_in[4];
    const int*   udeg = (const int*)d_in[5];
    const int*   odeg = (const int*)d_in[6];
    float* out = (float*)d_out;
    float* ws  = (float*)d_ws;

    prep_kernel<<<PREP_ELEM_BLOCKS + PREP_L_BLOCKS, 256, 0, stream>>>(
        ui, oi, posw, negw, bias, udeg, odeg, out, ws);
    main_kernel<<<PAIR_BLOCKS + TAIL_BLOCKS, 256, 0, stream>>>(
        ws + WS_POVER, ((const long long*)ws) + L_PART_LL, out);
}

// Round 8
// 46.604 us; speedup vs baseline: 1.5381x; 1.5381x over previous
//
#include <hip/hip_runtime.h>

// Problem constants (from reference): N_IN=16, T_IN=64, V=4, DEG=4 -> C=5, K=9
#define NINP 16
#define TIN 64
#define NV 4
#define NC 5
#define NK 9
#define T_ROWS 1025                 // 16*64 + 1 (const row)
#define NPAIR (1025 * 1025)         // 1,050,625
#define UNDER_SZ (T_ROWS * NV * NC) // 20500  (output 0)
#define OQ_OFF UNDER_SZ
#define OQ_SQ_SZ (NPAIR * NV * NK)          // 37,822,500
#define TAIL_ELEMS ((T_ROWS + 1) * NV * NK) // 36,936 (lin rows + const row)
#define DEG_OFF (OQ_OFF + OQ_SQ_SZ + TAIL_ELEMS) // 37,879,936
// ws layout: floats [0, 20500) = over polys; long-long partials at ll index 10252
#define WS_POVER 0
#define L_PART_LL 10252           // byte offset 82016, 8B aligned, past over polys
#define FIXED_SCALE 16777216.0f   // 2^24

#define PREP_ELEM_BLOCKS 161      // 161*256 = 41216 >= 2*20500
#define PREP_L_BLOCKS 4           // 4*256 = 1024 threads, rows 0..1023 (+row 1024 extra)
#define PAIR_BLOCKS 4105          // ceil(1050625/256)
#define TAIL_BLOCKS 145           // ceil(36936/256)

__device__ __forceinline__ int count_nz16(const float* __restrict__ w) {
    int c = 0;
#pragma unroll
    for (int n = 0; n < NINP; n++) c += (w[n] != 0.0f) ? 1 : 0;
    return c;
}

__device__ __forceinline__ int kth_nz16(const float* __restrict__ w, int k) {
    int c = 0, r = 0;
#pragma unroll
    for (int n = 0; n < NINP; n++) {
        bool nz = (w[n] != 0.0f);
        if (nz && c == k) r = n;
        c += nz ? 1 : 0;
    }
    return r;
}

// value of the `under` polynomial array at (row r, var v, coeff c)
__device__ __forceinline__ float under_val(const float* __restrict__ ui,
                                           const float* __restrict__ oi,
                                           const float* __restrict__ posw,
                                           const float* __restrict__ negw,
                                           float bias, int r, int v, int c) {
    if (r < 1024) {
        int g = r >> 6, tt = r & 63;
        int nNeg = count_nz16(negw);
        if (g < nNeg) {
            int n = kth_nz16(negw, g);
            return oi[((n * TIN + tt) * NV + v) * NC + c] * ((v == 0) ? negw[n] : 1.0f);
        }
        int n = kth_nz16(posw, g - nNeg);
        return ui[((n * TIN + tt) * NV + v) * NC + c] * ((v == 0) ? posw[n] : 1.0f);
    }
    return (v == 0) ? bias : 1.0f;
}

// Kernel 1: blocks [0,161): build `under` (-> d_out) and `over` (-> ws) + deg outputs.
//           blocks [161,165): interval lower bound per under-row, deterministic
//           fixed-point int64 block reduction -> 4 partials in ws.
__global__ __launch_bounds__(256) void prep_kernel(
    const float* __restrict__ ui, const float* __restrict__ oi,
    const float* __restrict__ posw, const float* __restrict__ negw,
    const float* __restrict__ bias,
    const int* __restrict__ udeg, const int* __restrict__ odeg,
    float* __restrict__ out, float* __restrict__ ws) {
    const int bid = blockIdx.x;
    const int t = threadIdx.x;

    if (bid < PREP_ELEM_BLOCKS) {
        int gid = bid * 256 + t;
        if (gid < NV) {
            int m = 0;
            for (int n = 0; n < NINP; n++) {
                int a = udeg[n * NV + gid];
                int b = odeg[n * NV + gid];
                m = max(m, max(a, b));
            }
            out[DEG_OFF + gid] = (float)m;
            out[DEG_OFF + NV + gid] = 2.0f * (float)m;
        }
        if (gid < UNDER_SZ) {
            int r = gid / 20, rem = gid - r * 20, v = rem / 5, c = rem - v * 5;
            out[gid] = under_val(ui, oi, posw, negw, bias[0], r, v, c);
        } else if (gid < 2 * UNDER_SZ) {
            // over element: rows = [over_in[pos]*pos_w ; under_in[neg]*neg_w ; const]
            int e = gid - UNDER_SZ;
            int r = e / 20, rem = e - r * 20, v = rem / 5, c = rem - v * 5;
            float val;
            if (r < 1024) {
                int g = r >> 6, tt = r & 63;
                int nPos = count_nz16(posw);
                if (g < nPos) {
                    int n = kth_nz16(posw, g);
                    val = oi[((n * TIN + tt) * NV + v) * NC + c] * ((v == 0) ? posw[n] : 1.0f);
                } else {
                    int n = kth_nz16(negw, g - nPos);
                    val = ui[((n * TIN + tt) * NV + v) * NC + c] * ((v == 0) ? negw[n] : 1.0f);
                }
            } else {
                val = (v == 0) ? bias[0] : 1.0f;
            }
            ws[WS_POVER + e] = val;
        }
    } else {
        // l partial: rows (bid-161)*256 + t, deterministic fixed-point sum
        __shared__ long long s[256];
        const float b0 = bias[0];
        int r = (bid - PREP_ELEM_BLOCKS) * 256 + t;
        float tlo = 0.f, thi = 0.f;
#pragma unroll
        for (int v = 0; v < NV; v++) {
            float lo = under_val(ui, oi, posw, negw, b0, r, v, 0), hi = lo;
#pragma unroll
            for (int c = 1; c < NC; c++) {
                float x = under_val(ui, oi, posw, negw, b0, r, v, c);
                lo = fminf(lo, x);
                hi = fmaxf(hi, x);
            }
            if (v == 0) { tlo = lo; thi = hi; }
            else {
                float p0 = tlo * lo, p1 = tlo * hi, p2 = thi * lo, p3 = thi * hi;
                tlo = fminf(fminf(p0, p1), fminf(p2, p3));
                thi = fmaxf(fmaxf(p0, p1), fmaxf(p2, p3));
            }
        }
        long long acc = __float2ll_rn(tlo * FIXED_SCALE);
        if (bid == PREP_ELEM_BLOCKS && t == 0) {
            // const row 1024: interval product = bias (all other vars are exactly 1)
            acc += __float2ll_rn(b0 * FIXED_SCALE);
        }
        s[t] = acc;
        __syncthreads();
        for (int off = 128; off > 0; off >>= 1) {
            if (t < off) s[t] += s[t + off];
            __syncthreads();
        }
        if (t == 0) ((long long*)ws)[L_PART_LL + (bid - PREP_ELEM_BLOCKS)] = s[0];
    }
}

// Kernel 2: the 1025^2 pair-product rows. One thread = one (a,b) pair = 36 outputs,
// staged through padded LDS for fully-coalesced linear stores. (r1 champion path.)
__global__ __launch_bounds__(256) void sq_kernel(const float* __restrict__ P,
                                                 const long long* __restrict__ lpart,
                                                 float* __restrict__ out) {
    __shared__ float lds[256 * 37]; // stride 37 coprime with 32 banks -> conflict-free
    const int t = threadIdx.x;
    const int p0 = blockIdx.x * 256;
    int nvalid = NPAIR - p0;
    if (nvalid > 256) nvalid = 256;
    const long long llv = lpart[0] + lpart[1] + lpart[2] + lpart[3];
    const float l = (float)llv * (1.0f / FIXED_SCALE);
    const float ascale = -0.25f / l; // a = 1/(-4l)

    if (t < nvalid) {
        int p = p0 + t;
        int ai = p / 1025;
        int bi = p - ai * 1025;
        float pa[20], pb[20];
        const float4* A4 = reinterpret_cast<const float4*>(P + ai * 20);
        const float4* B4 = reinterpret_cast<const float4*>(P + bi * 20);
#pragma unroll
        for (int q = 0; q < 5; q++) {
            float4 x = A4[q];
            pa[4 * q] = x.x; pa[4 * q + 1] = x.y; pa[4 * q + 2] = x.z; pa[4 * q + 3] = x.w;
            float4 y = B4[q];
            pb[4 * q] = y.x; pb[4 * q + 1] = y.y; pb[4 * q + 2] = y.z; pb[4 * q + 3] = y.w;
        }
        const float invC8[9] = {1.f, 0.125f, 1.f / 28.f, 1.f / 56.f, 1.f / 70.f,
                                1.f / 56.f, 1.f / 28.f, 0.125f, 1.f};
#pragma unroll
        for (int v = 0; v < NV; v++) {
            float a_[5], b_[5];
#pragma unroll
            for (int i = 0; i < 5; i++) {
                const float c4 = (i == 0 || i == 4) ? 1.f : ((i == 2) ? 6.f : 4.f);
                a_[i] = pa[v * 5 + i] * c4;
                b_[i] = pb[v * 5 + i] * c4;
            }
            float cc[9];
#pragma unroll
            for (int k = 0; k < 9; k++) cc[k] = 0.f;
#pragma unroll
            for (int i = 0; i < 5; i++)
#pragma unroll
                for (int j = 0; j < 5; j++) cc[i + j] += a_[i] * b_[j];
            const float sc = (v == 0) ? ascale : 1.0f;
#pragma unroll
            for (int k = 0; k < 9; k++) lds[t * 37 + v * 9 + k] = cc[k] * invC8[k] * sc;
        }
    }
    __syncthreads();

    const int nflt = nvalid * 36;
    const long base = (long)OQ_OFF + (long)p0 * 36;
    int f = t;
    int pl = f / 36, w = f - pl * 36;
    for (; f < nflt; f += 256) {
        out[base + f] = lds[pl * 37 + w];
        pl += 7; w += 4;            // 256 = 7*36 + 4
        if (w >= 36) { w -= 36; pl++; }
    }
}

__device__ __forceinline__ float c4_of(int j) {
    if (j == 0 || j == 4) return 1.f;
    if (j == 1 || j == 3) return 4.f;
    if (j == 2) return 6.f;
    return 0.f;
}

// Kernel 3: 1025 elevated-linear rows (P * E_ELEV, v0 scaled by b=0.5) + 1 const row
__global__ void tail_kernel(const float* __restrict__ P,
                            const long long* __restrict__ lpart,
                            float* __restrict__ out) {
    int idx = blockIdx.x * blockDim.x + threadIdx.x;
    if (idx >= TAIL_ELEMS) return;
    const long long llv = lpart[0] + lpart[1] + lpart[2] + lpart[3];
    const float l = (float)llv * (1.0f / FIXED_SCALE);
    int rl = idx / 36, rem = idx - rl * 36, v = rem / 9, k = rem - v * 9;
    const float invC8[9] = {1.f, 0.125f, 1.f / 28.f, 1.f / 56.f, 1.f / 70.f,
                            1.f / 56.f, 1.f / 28.f, 0.125f, 1.f};
    const float C4[5] = {1.f, 4.f, 6.f, 4.f, 1.f};
    float val;
    if (rl < T_ROWS) {
        float acc = 0.f;
#pragma unroll
        for (int i = 0; i < 5; i++) {
            float e = C4[i] * c4_of(k - i); // E[i,k] numerator; 0 out of band
            acc += P[rl * 20 + v * 5 + i] * e;
        }
        val = acc * invC8[k] * ((v == 0) ? 0.5f : 1.0f);
    } else {
        val = (v == 0) ? (-0.25f * l) : 1.0f; // c = -l/4
    }
    out[OQ_OFF + (long)NPAIR * 36 + idx] = val;
}

extern "C" void kernel_launch(void* const* d_in, const int* in_sizes, int n_in,
                              void* d_out, int out_size, void* d_ws, size_t ws_size,
                              hipStream_t stream) {
    const float* ui   = (const float*)d_in[0];
    const float* oi   = (const float*)d_in[1];
    const float* posw = (const float*)d_in[2];
    const float* negw = (const float*)d_in[3];
    const float* bias = (const float*)d_in[4];
    const int*   udeg = (const int*)d_in[5];
    const int*   odeg = (const int*)d_in[6];
    float* out = (float*)d_out;
    float* ws  = (float*)d_ws;

    prep_kernel<<<PREP_ELEM_BLOCKS + PREP_L_BLOCKS, 256, 0, stream>>>(
        ui, oi, posw, negw, bias, udeg, odeg, out, ws);
    sq_kernel<<<PAIR_BLOCKS, 256, 0, stream>>>(
        ws + WS_POVER, ((const long long*)ws) + L_PART_LL, out);
    tail_kernel<<<TAIL_BLOCKS, 256, 0, stream>>>(
        ws + WS_POVER, ((const long long*)ws) + L_PART_LL, out);
}

// Round 9
// 41.989 us; speedup vs baseline: 1.7072x; 1.1099x over previous
//
#include <hip/hip_runtime.h>

// Problem constants (from reference): N_IN=16, T_IN=64, V=4, DEG=4 -> C=5, K=9
#define NINP 16
#define TIN 64
#define NV 4
#define NC 5
#define NK 9
#define T_ROWS 1025                 // 16*64 + 1 (const row)
#define NPAIR (1025 * 1025)         // 1,050,625
#define UNDER_SZ (T_ROWS * NV * NC) // 20500  (output 0)
#define OQ_OFF UNDER_SZ
#define OQ_SQ_SZ (NPAIR * NV * NK)        // 37,822,500
#define TAIL_ELEMS ((T_ROWS + 1) * NV * NK) // 36,936 (lin rows + const row)
#define DEG_OFF (OQ_OFF + OQ_SQ_SZ + TAIL_ELEMS) // 37,879,936
// ws float layout
#define WS_POVER 0
#define WS_L 20500

__device__ __forceinline__ int count_nz16(const float* __restrict__ w) {
    int c = 0;
#pragma unroll
    for (int n = 0; n < NINP; n++) c += (w[n] != 0.0f) ? 1 : 0;
    return c;
}

__device__ __forceinline__ int kth_nz16(const float* __restrict__ w, int k) {
    int c = 0, r = 0;
#pragma unroll
    for (int n = 0; n < NINP; n++) {
        bool nz = (w[n] != 0.0f);
        if (nz && c == k) r = n;
        c += nz ? 1 : 0;
    }
    return r;
}

// Kernel A: build `under` (-> d_out[0:20500]) and `over` (-> ws) poly arrays,
// plus deg / 2*deg outputs.
__global__ void prep_kernel(const float* __restrict__ ui, const float* __restrict__ oi,
                            const float* __restrict__ posw, const float* __restrict__ negw,
                            const float* __restrict__ bias,
                            const int* __restrict__ udeg, const int* __restrict__ odeg,
                            float* __restrict__ out, float* __restrict__ ws) {
    int gid = blockIdx.x * blockDim.x + threadIdx.x;
    if (gid < NV) {
        int m = 0;
        for (int n = 0; n < NINP; n++) {
            int a = udeg[n * NV + gid];
            int b = odeg[n * NV + gid];
            m = max(m, max(a, b));
        }
        out[DEG_OFF + gid] = (float)m;
        out[DEG_OFF + NV + gid] = 2.0f * (float)m;
    }
    if (gid < UNDER_SZ) {
        // under element: rows = [over_in[neg_idx]*neg_w ; under_in[pos_idx]*pos_w ; const(bias)]
        int r = gid / 20, rem = gid - r * 20, v = rem / 5, c = rem - v * 5;
        float val;
        if (r < 1024) {
            int g = r >> 6, t = r & 63;
            int nNeg = count_nz16(negw);
            if (g < nNeg) {
                int n = kth_nz16(negw, g);
                val = oi[((n * TIN + t) * NV + v) * NC + c] * ((v == 0) ? negw[n] : 1.0f);
            } else {
                int n = kth_nz16(posw, g - nNeg);
                val = ui[((n * TIN + t) * NV + v) * NC + c] * ((v == 0) ? posw[n] : 1.0f);
            }
        } else {
            val = (v == 0) ? bias[0] : 1.0f;
        }
        out[gid] = val;
    } else if (gid < 2 * UNDER_SZ) {
        // over element: rows = [over_in[pos_idx]*pos_w ; under_in[neg_idx]*neg_w ; const(bias)]
        int e = gid - UNDER_SZ;
        int r = e / 20, rem = e - r * 20, v = rem / 5, c = rem - v * 5;
        float val;
        if (r < 1024) {
            int g = r >> 6, t = r & 63;
            int nPos = count_nz16(posw);
            if (g < nPos) {
                int n = kth_nz16(posw, g);
                val = oi[((n * TIN + t) * NV + v) * NC + c] * ((v == 0) ? posw[n] : 1.0f);
            } else {
                int n = kth_nz16(negw, g - nPos);
                val = ui[((n * TIN + t) * NV + v) * NC + c] * ((v == 0) ? negw[n] : 1.0f);
            }
        } else {
            val = (v == 0) ? bias[0] : 1.0f;
        }
        ws[WS_POVER + e] = val;
    }
}

// interval lower bound of the product of V per-variable coefficient intervals
__device__ __forceinline__ float row_lower(const float* __restrict__ P, int r) {
    const float* row = P + r * 20;
    float tlo = 0.f, thi = 0.f;
#pragma unroll
    for (int v = 0; v < NV; v++) {
        float lo = row[v * 5], hi = lo;
#pragma unroll
        for (int c = 1; c < 5; c++) {
            float x = row[v * 5 + c];
            lo = fminf(lo, x);
            hi = fmaxf(hi, x);
        }
        if (v == 0) {
            tlo = lo; thi = hi;
        } else {
            float p0 = tlo * lo, p1 = tlo * hi, p2 = thi * lo, p3 = thi * hi;
            tlo = fminf(fminf(p0, p1), fminf(p2, p3));
            thi = fmaxf(fmaxf(p0, p1), fmaxf(p2, p3));
        }
    }
    return tlo;
}

// Kernel B: l = sum over 1025 rows of interval-product lower bound (deterministic tree)
__global__ __launch_bounds__(1024) void reduce_l_kernel(const float* __restrict__ under,
                                                        float* __restrict__ ws) {
    __shared__ float s[1024];
    int t = threadIdx.x;
    float acc = row_lower(under, t);
    if (t == 0) acc += row_lower(under, 1024);
    s[t] = acc;
    __syncthreads();
    for (int off = 512; off > 0; off >>= 1) {
        if (t < off) s[t] += s[t + off];
        __syncthreads();
    }
    if (t == 0) ws[WS_L] = s[0];
}

// Kernel C: the 1025^2 pair-product rows. One thread = one (a,b) pair = 36 outputs,
// staged through padded LDS for fully-coalesced linear stores.
__global__ __launch_bounds__(256) void sq_kernel(const float* __restrict__ P,
                                                 const float* __restrict__ lptr,
                                                 float* __restrict__ out) {
    __shared__ float lds[256 * 37]; // stride 37 coprime with 32 banks -> conflict-free
    const int t = threadIdx.x;
    const int p0 = blockIdx.x * 256;
    int nvalid = NPAIR - p0;
    if (nvalid > 256) nvalid = 256;
    const float l = lptr[0];
    const float ascale = -0.25f / l; // a = 1/(-4l)

    if (t < nvalid) {
        int p = p0 + t;
        int ai = p / 1025;
        int bi = p - ai * 1025;
        float pa[20], pb[20];
        const float4* A4 = reinterpret_cast<const float4*>(P + ai * 20);
        const float4* B4 = reinterpret_cast<const float4*>(P + bi * 20);
#pragma unroll
        for (int q = 0; q < 5; q++) {
            float4 x = A4[q];
            pa[4 * q] = x.x; pa[4 * q + 1] = x.y; pa[4 * q + 2] = x.z; pa[4 * q + 3] = x.w;
            float4 y = B4[q];
            pb[4 * q] = y.x; pb[4 * q + 1] = y.y; pb[4 * q + 2] = y.z; pb[4 * q + 3] = y.w;
        }
        const float C4[5] = {1.f, 4.f, 6.f, 4.f, 1.f};
        const float invC8[9] = {1.f, 0.125f, 1.f / 28.f, 1.f / 56.f, 1.f / 70.f,
                                1.f / 56.f, 1.f / 28.f, 0.125f, 1.f};
#pragma unroll
        for (int v = 0; v < NV; v++) {
            float a_[5], b_[5];
#pragma unroll
            for (int i = 0; i < 5; i++) {
                a_[i] = pa[v * 5 + i] * C4[i];
                b_[i] = pb[v * 5 + i] * C4[i];
            }
            float cc[9];
#pragma unroll
            for (int k = 0; k < 9; k++) cc[k] = 0.f;
#pragma unroll
            for (int i = 0; i < 5; i++)
#pragma unroll
                for (int j = 0; j < 5; j++) cc[i + j] += a_[i] * b_[j];
            const float sc = (v == 0) ? ascale : 1.0f;
#pragma unroll
            for (int k = 0; k < 9; k++) lds[t * 37 + v * 9 + k] = cc[k] * invC8[k] * sc;
        }
    }
    __syncthreads();

    const int nflt = nvalid * 36;
    const long base = (long)OQ_OFF + (long)p0 * 36;
    int f = t;
    int pl = f / 36, w = f - pl * 36;
    for (; f < nflt; f += 256) {
        out[base + f] = lds[pl * 37 + w];
        pl += 7; w += 4;            // 256 = 7*36 + 4
        if (w >= 36) { w -= 36; pl++; }
    }
}

__device__ __forceinline__ float c4_of(int j) {
    // C(4,j) with 0 outside [0,4], branchless-ish selects
    if (j == 0 || j == 4) return 1.f;
    if (j == 1 || j == 3) return 4.f;
    if (j == 2) return 6.f;
    return 0.f;
}

// Kernel D: 1025 elevated-linear rows (P * E_ELEV, v0 scaled by b=0.5) + 1 const row (c, 1,1,1)
__global__ void tail_kernel(const float* __restrict__ P, const float* __restrict__ lptr,
                            float* __restrict__ out) {
    int idx = blockIdx.x * blockDim.x + threadIdx.x;
    if (idx >= TAIL_ELEMS) return;
    int rl = idx / 36, rem = idx - rl * 36, v = rem / 9, k = rem - v * 9;
    const float invC8[9] = {1.f, 0.125f, 1.f / 28.f, 1.f / 56.f, 1.f / 70.f,
                            1.f / 56.f, 1.f / 28.f, 0.125f, 1.f};
    const float C4[5] = {1.f, 4.f, 6.f, 4.f, 1.f};
    float val;
    if (rl < T_ROWS) {
        float acc = 0.f;
#pragma unroll
        for (int i = 0; i < 5; i++) {
            float e = C4[i] * c4_of(k - i); // E[i,k] numerator; 0 out of band
            acc += P[rl * 20 + v * 5 + i] * e;
        }
        val = acc * invC8[k] * ((v == 0) ? 0.5f : 1.0f);
    } else {
        val = (v == 0) ? (-0.25f * lptr[0]) : 1.0f; // c = -l/4
    }
    out[OQ_OFF + (long)NPAIR * 36 + idx] = val;
}

extern "C" void kernel_launch(void* const* d_in, const int* in_sizes, int n_in,
                              void* d_out, int out_size, void* d_ws, size_t ws_size,
                              hipStream_t stream) {
    const float* ui   = (const float*)d_in[0];
    const float* oi   = (const float*)d_in[1];
    const float* posw = (const float*)d_in[2];
    const float* negw = (const float*)d_in[3];
    const float* bias = (const float*)d_in[4];
    const int*   udeg = (const int*)d_in[5];
    const int*   odeg = (const int*)d_in[6];
    float* out = (float*)d_out;
    float* ws  = (float*)d_ws;

    prep_kernel<<<(2 * UNDER_SZ + 255) / 256, 256, 0, stream>>>(ui, oi, posw, negw, bias,
                                                                udeg, odeg, out, ws);
    reduce_l_kernel<<<1, 1024, 0, stream>>>(out, ws);
    sq_kernel<<<(NPAIR + 255) / 256, 256, 0, stream>>>(ws + WS_POVER, ws + WS_L, out);
    tail_kernel<<<(TAIL_ELEMS + 255) / 256, 256, 0, stream>>>(ws + WS_POVER, ws + WS_L, out);
}